// Round 10
// baseline (1045.104 us; speedup 1.0000x reference)
//
#include <hip/hip_runtime.h>
#include <hip/hip_bf16.h>
#include <math.h>

namespace {

constexpr int B  = 256;
constexpr int N  = 64;
constexpr int D  = 512;
constexpr int H  = 8;
constexpr int NBLK = 4;
constexpr int M  = B * N;
constexpr float EPS = 1e-5f;
constexpr float SCALE = 0.125f;
constexpr int NEVER = 1 << 20;

typedef __attribute__((ext_vector_type(8))) short short8b;
typedef __attribute__((ext_vector_type(4))) float f32x4;

__device__ __forceinline__ float gelu_exact(float x) {
  return 0.5f * x * (1.0f + erff(x * 0.70710678118654752440f));
}

__device__ __forceinline__ unsigned short f2b_bits(float f) {
  __hip_bfloat16 h = __float2bfloat16(f);
  return *reinterpret_cast<unsigned short*>(&h);
}

#define GLOBAL_AS __attribute__((address_space(1)))
#define LDS_AS    __attribute__((address_space(3)))

__device__ __forceinline__ void gload_lds16(const void* g, void* l) {
  __builtin_amdgcn_global_load_lds((const GLOBAL_AS void*)g, (LDS_AS void*)l, 16, 0, 0);
}

__device__ __forceinline__ void barrier_pinned() {
  __builtin_amdgcn_sched_barrier(0);
  __builtin_amdgcn_s_barrier();
  __builtin_amdgcn_sched_barrier(0);
}

// ---------------------------------------------------------------------------
// gemm_dp2b: 256x256 tile, K split into 16 super-phases of BK=32.
// 4 LDS buffers (32 KB each: A[256][32] @0, B[256][32] @16K) = 128 KB.
// Super-phase s: STAGE(s+2) -> vmcnt(8) (waits only buffer s; s+1,s+2 stay
// in flight -> true counted pipeline, no drain until the tail) -> barrier ->
// 12 ds_read -> 32 MFMA (setprio). One barrier per super-phase.
// 8 waves (2M x 4N), 128x64 per wave, acc[8][4].
// ---------------------------------------------------------------------------
template<bool GELU, int SPLIT>
__global__ __launch_bounds__(512) void gemm_dp2b_kernel(
    const __hip_bfloat16* __restrict__ A,
    const __hip_bfloat16* __restrict__ Wt,
    const float* __restrict__ bias,
    __hip_bfloat16* __restrict__ out1, int ostr1,
    __hip_bfloat16* __restrict__ vt, int gy) {
  constexpr int K = 512;
  constexpr int NS = 16;                       // 8 K-tiles x 2 k-halves
  __shared__ __align__(16) char lds[4][32768]; // per buf: A 16KB, B 16KB

  const int nwg = gridDim.x;
  const int hw  = blockIdx.x;
  const int cpx = nwg >> 3;
  const int lg  = (hw & 7) * cpx + (hw >> 3);
  const int bm  = (lg / gy) * 256;
  const int bn  = (lg % gy) * 256;

  const int tid  = threadIdx.x;
  const int wave = tid >> 6;
  const int lane = tid & 63;
  const int wm   = (wave >> 2) * 128;   // 0 or 128
  const int wn   = (wave & 3) * 64;     // 0..192
  const int fr   = lane & 15;
  const int fg   = lane >> 4;

  // Staging: per buffer, 2 row-groups (r=0: rows 0-127, r=1: 128-255);
  // lane covers row r*128 + wave*16 + (lane>>2), 16B slot lane&3.
  // Source slot inverse-swizzled (^ row&3) so linear LDS writes give
  // swizzled-read content (rule #21 both-sides involution).
  const int strow0 = wave * 16 + (lane >> 2);

  auto STAGE = [&](int s) {
    const int buf = s & 3;
    const int ko  = (s >> 1) * 64 + (s & 1) * 32;
#pragma unroll
    for (int r = 0; r < 2; ++r) {
      const int row = r * 128 + strow0;
      const int sl  = (lane & 3) ^ (row & 3);
      gload_lds16(A  + (size_t)(bm + row) * K + ko + sl * 8,
                  &lds[buf][r * 8192 + wave * 1024]);
      gload_lds16(Wt + (size_t)(bn + row) * K + ko + sl * 8,
                  &lds[buf][16384 + r * 8192 + wave * 1024]);
    }
  };

  auto ldA = [&](int s, int row) -> short8b {
    const int byte = row * 64 + ((fg ^ (row & 3)) << 4);
    return *reinterpret_cast<const short8b*>(&lds[s & 3][byte]);
  };
  auto ldB = [&](int s, int row) -> short8b {
    const int byte = 16384 + row * 64 + ((fg ^ (row & 3)) << 4);
    return *reinterpret_cast<const short8b*>(&lds[s & 3][byte]);
  };

  STAGE(0);
  STAGE(1);

  f32x4 acc[8][4] = {};
  for (int s = 0; s < NS; ++s) {
    if (s + 2 < NS) STAGE(s + 2);
    // Gate: buffer s landed; buffers s+1, s+2 (4 loads each) stay in flight.
    if (s + 2 < NS)      { asm volatile("s_waitcnt vmcnt(8)" ::: "memory"); }
    else if (s + 1 < NS) { asm volatile("s_waitcnt vmcnt(4)" ::: "memory"); }
    else                 { asm volatile("s_waitcnt vmcnt(0)" ::: "memory"); }
    barrier_pinned();

    short8b af[8], bf_[4];
#pragma unroll
    for (int mi = 0; mi < 8; ++mi) af[mi] = ldA(s, wm + mi * 16 + fr);
#pragma unroll
    for (int ni = 0; ni < 4; ++ni) bf_[ni] = ldB(s, wn + ni * 16 + fr);

    __builtin_amdgcn_s_setprio(1);
#pragma unroll
    for (int mi = 0; mi < 8; ++mi)
#pragma unroll
      for (int ni = 0; ni < 4; ++ni)
        acc[mi][ni] = __builtin_amdgcn_mfma_f32_16x16x32_bf16(af[mi], bf_[ni], acc[mi][ni], 0, 0, 0);
    __builtin_amdgcn_s_setprio(0);
  }

  // Epilogue. C/D: col = lane&15, row = (lane>>4)*4 + reg.
#pragma unroll
  for (int ni = 0; ni < 4; ++ni) {
    const int col = bn + wn + ni * 16 + fr;
    const float bv = bias ? bias[col] : 0.f;
#pragma unroll
    for (int mi = 0; mi < 8; ++mi) {
      const int row0 = bm + wm + mi * 16 + fg * 4;
      if (col >= SPLIT) {
        const int vcol = col - SPLIT;
        ushort4 o;
        o.x = f2b_bits(acc[mi][ni][0] + bv);
        o.y = f2b_bits(acc[mi][ni][1] + bv);
        o.z = f2b_bits(acc[mi][ni][2] + bv);
        o.w = f2b_bits(acc[mi][ni][3] + bv);
        const int b8 = row0 >> 6, nl = row0 & 63;
        const int hh = vcol >> 6, dl = vcol & 63;
        *reinterpret_cast<ushort4*>(vt +
            ((size_t)(b8 * 8 + hh) * 4096 + dl * 64 + nl)) = o;
      } else {
#pragma unroll
        for (int q = 0; q < 4; ++q) {
          float v = acc[mi][ni][q] + bv;
          if (GELU) v = gelu_exact(v);
          out1[(size_t)(row0 + q) * ostr1 + col] = __float2bfloat16(v);
        }
      }
    }
  }
}

// ---------------------------------------------------------------------------
// Deep-pipelined bf16 MFMA GEMM, 128x256 tile (proven) — kept for w1.
// ---------------------------------------------------------------------------
template<bool GELU, int SPLIT>
__global__ __launch_bounds__(512, 2) void gemm_dp_kernel(
    const __hip_bfloat16* __restrict__ A,
    const __hip_bfloat16* __restrict__ Wt,
    const float* __restrict__ bias,
    __hip_bfloat16* __restrict__ out1, int ostr1,
    __hip_bfloat16* __restrict__ vt, int gy) {
  constexpr int K = 512;
  constexpr int NT = 8;
  __shared__ __hip_bfloat16 Als[3][128][64];
  __shared__ __hip_bfloat16 Bls[3][256][64];

  const int nwg = gridDim.x;
  const int hw  = blockIdx.x;
  const int cpx = nwg >> 3;
  const int lg  = (hw & 7) * cpx + (hw >> 3);
  const int bm  = (lg / gy) * 128;
  const int bn  = (lg % gy) * 256;

  const int tid  = threadIdx.x;
  const int wave = tid >> 6;
  const int lane = tid & 63;
  const int wm   = (wave >> 2) * 64;
  const int wn   = (wave & 3) * 64;
  const int fr   = lane & 15;
  const int fg   = lane >> 4;

  const int srow  = tid >> 3;
  const int sslot = (tid & 7) ^ (srow & 7);
  const __hip_bfloat16* gA = A  + (size_t)(bm + srow) * K + sslot * 8;
  const __hip_bfloat16* gB = Wt + (size_t)(bn + srow) * K + sslot * 8;

  auto STAGE = [&](int buf, int kt) {
    const int ko = kt * 64;
    char* la = (char*)&Als[buf][0][0] + wave * 1024;
    char* lb = (char*)&Bls[buf][0][0] + wave * 1024;
    gload_lds16(gA + ko,           la);
    gload_lds16(gA + 64 * K + ko,  la + 8192);
    gload_lds16(gB + ko,           lb);
    gload_lds16(gB + 64 * K + ko,  lb + 8192);
    gload_lds16(gB + 128 * K + ko, lb + 16384);
    gload_lds16(gB + 192 * K + ko, lb + 24576);
  };

  auto lda = [&](int buf, int mi, int ks) -> short8b {
    const int row  = wm + mi * 16 + fr;
    const int byte = row * 128 + (((ks << 2) | fg) ^ (fr & 7)) * 16;
    return *reinterpret_cast<const short8b*>((const char*)&Als[buf][0][0] + byte);
  };
  auto ldb = [&](int buf, int ni, int ks) -> short8b {
    const int row  = wn + ni * 16 + fr;
    const int byte = row * 128 + (((ks << 2) | fg) ^ (fr & 7)) * 16;
    return *reinterpret_cast<const short8b*>((const char*)&Bls[buf][0][0] + byte);
  };

  STAGE(0, 0);
  STAGE(1, 1);
  asm volatile("s_waitcnt vmcnt(6)" ::: "memory");
  barrier_pinned();

  f32x4 acc[4][4] = {};
  for (int t = 0; t < NT; ++t) {
    const int cur = t % 3;
    if (t + 2 < NT) STAGE((t + 2) % 3, t + 2);

    short8b a0[4], b0[4], a1[4], b1[4];
#pragma unroll
    for (int mi = 0; mi < 4; ++mi) a0[mi] = lda(cur, mi, 0);
#pragma unroll
    for (int ni = 0; ni < 4; ++ni) b0[ni] = ldb(cur, ni, 0);
#pragma unroll
    for (int mi = 0; mi < 4; ++mi) a1[mi] = lda(cur, mi, 1);
#pragma unroll
    for (int ni = 0; ni < 4; ++ni) b1[ni] = ldb(cur, ni, 1);

    __builtin_amdgcn_s_setprio(1);
#pragma unroll
    for (int mi = 0; mi < 4; ++mi)
#pragma unroll
      for (int ni = 0; ni < 4; ++ni)
        acc[mi][ni] = __builtin_amdgcn_mfma_f32_16x16x32_bf16(a0[mi], b0[ni], acc[mi][ni], 0, 0, 0);
#pragma unroll
    for (int mi = 0; mi < 4; ++mi)
#pragma unroll
      for (int ni = 0; ni < 4; ++ni)
        acc[mi][ni] = __builtin_amdgcn_mfma_f32_16x16x32_bf16(a1[mi], b1[ni], acc[mi][ni], 0, 0, 0);
    __builtin_amdgcn_s_setprio(0);

    if (t + 2 < NT) {
      asm volatile("s_waitcnt vmcnt(6)" ::: "memory");
    } else {
      asm volatile("s_waitcnt vmcnt(0)" ::: "memory");
    }
    barrier_pinned();
  }

#pragma unroll
  for (int ni = 0; ni < 4; ++ni) {
    const int col = bn + wn + ni * 16 + fr;
    const float bv = bias ? bias[col] : 0.f;
#pragma unroll
    for (int mi = 0; mi < 4; ++mi) {
      const int row0 = bm + wm + mi * 16 + fg * 4;
      if (col >= SPLIT) {
        const int vcol = col - SPLIT;
        ushort4 o;
        o.x = f2b_bits(acc[mi][ni][0] + bv);
        o.y = f2b_bits(acc[mi][ni][1] + bv);
        o.z = f2b_bits(acc[mi][ni][2] + bv);
        o.w = f2b_bits(acc[mi][ni][3] + bv);
        const int b8 = row0 >> 6, nl = row0 & 63;
        const int hh = vcol >> 6, dl = vcol & 63;
        *reinterpret_cast<ushort4*>(vt +
            ((size_t)(b8 * 8 + hh) * 4096 + dl * 64 + nl)) = o;
      } else {
#pragma unroll
        for (int q = 0; q < 4; ++q) {
          float v = acc[mi][ni][q] + bv;
          if (GELU) v = gelu_exact(v);
          out1[(size_t)(row0 + q) * ostr1 + col] = __float2bfloat16(v);
        }
      }
    }
  }
}

// ---------------------------------------------------------------------------
// GEMM + bias (+GELU) + bf16 residual + LN, BK=64 swizzled (K=512). Proven.
// ---------------------------------------------------------------------------
template<bool GELU_PRE, bool RES>
__global__ __launch_bounds__(512) void gemm_ln64_kernel(
    const __hip_bfloat16* __restrict__ A,
    const __hip_bfloat16* __restrict__ Wt,
    const float* __restrict__ bias,
    const __hip_bfloat16* __restrict__ resb,
    const float* __restrict__ g, const float* __restrict__ bb,
    __hip_bfloat16* __restrict__ outB) {
  __shared__ __hip_bfloat16 Als[2][64][64];
  __shared__ __hip_bfloat16 Bls[2][512][64];
  __shared__ float red[64][8];
  __shared__ float mrow[64];
  __shared__ float rrow[64];

  const int bm   = blockIdx.x * 64;
  const int tid  = threadIdx.x;
  const int wave = tid >> 6;
  const int lane = tid & 63;
  const int fr   = lane & 15;
  const int fg   = lane >> 4;

  const int srow  = tid >> 3;
  const int sslot = (tid & 7) ^ (srow & 7);

  auto stage = [&](int buf, int kt) {
    const int ko = kt * 64;
    gload_lds16(A + (size_t)(bm + srow) * 512 + ko + sslot * 8,
                (char*)&Als[buf][0][0] + wave * 1024);
#pragma unroll
    for (int j = 0; j < 8; ++j) {
      const int row = j * 64 + srow;
      const int sl  = (tid & 7) ^ (row & 7);
      gload_lds16(Wt + (size_t)row * 512 + ko + sl * 8,
                  (char*)&Bls[buf][0][0] + j * 8192 + wave * 1024);
    }
  };

  auto lda = [&](int buf, int mi, int ks) -> short8b {
    const int row  = mi * 16 + fr;
    const int byte = row * 128 + (((ks << 2) | fg) ^ (row & 7)) * 16;
    return *reinterpret_cast<const short8b*>((const char*)&Als[buf][0][0] + byte);
  };
  auto ldb = [&](int buf, int ni, int ks) -> short8b {
    const int row  = wave * 64 + ni * 16 + fr;
    const int byte = row * 128 + (((ks << 2) | fg) ^ (row & 7)) * 16;
    return *reinterpret_cast<const short8b*>((const char*)&Bls[buf][0][0] + byte);
  };

  f32x4 acc[4][4] = {};
  stage(0, 0);
  int buf = 0;
  for (int kt = 0; kt < 8; ++kt) {
    __syncthreads();
    if (kt + 1 < 8) stage(buf ^ 1, kt + 1);
    short8b a0[4], b0[4], a1[4], b1[4];
#pragma unroll
    for (int mi = 0; mi < 4; ++mi) a0[mi] = lda(buf, mi, 0);
#pragma unroll
    for (int ni = 0; ni < 4; ++ni) b0[ni] = ldb(buf, ni, 0);
#pragma unroll
    for (int mi = 0; mi < 4; ++mi) a1[mi] = lda(buf, mi, 1);
#pragma unroll
    for (int ni = 0; ni < 4; ++ni) b1[ni] = ldb(buf, ni, 1);
    __builtin_amdgcn_s_setprio(1);
#pragma unroll
    for (int mi = 0; mi < 4; ++mi)
#pragma unroll
      for (int ni = 0; ni < 4; ++ni)
        acc[mi][ni] = __builtin_amdgcn_mfma_f32_16x16x32_bf16(a0[mi], b0[ni], acc[mi][ni], 0, 0, 0);
#pragma unroll
    for (int mi = 0; mi < 4; ++mi)
#pragma unroll
      for (int ni = 0; ni < 4; ++ni)
        acc[mi][ni] = __builtin_amdgcn_mfma_f32_16x16x32_bf16(a1[mi], b1[ni], acc[mi][ni], 0, 0, 0);
    __builtin_amdgcn_s_setprio(0);
    buf ^= 1;
  }

  float v[4][4][4];
  float bvc[4];
#pragma unroll
  for (int ni = 0; ni < 4; ++ni)
    bvc[ni] = bias ? bias[wave * 64 + ni * 16 + fr] : 0.f;
#pragma unroll
  for (int mi = 0; mi < 4; ++mi)
#pragma unroll
    for (int q = 0; q < 4; ++q) {
      const int row = bm + mi * 16 + fg * 4 + q;
#pragma unroll
      for (int ni = 0; ni < 4; ++ni) {
        float t = acc[mi][ni][q] + bvc[ni];
        if (GELU_PRE) t = gelu_exact(t);
        if (RES)
          t += __bfloat162float(resb[(size_t)row * D + wave * 64 + ni * 16 + fr]);
        v[mi][ni][q] = t;
      }
    }

  float ps[16];
#pragma unroll
  for (int mi = 0; mi < 4; ++mi)
#pragma unroll
    for (int q = 0; q < 4; ++q)
      ps[mi * 4 + q] = v[mi][0][q] + v[mi][1][q] + v[mi][2][q] + v[mi][3][q];
#pragma unroll
  for (int mask = 1; mask < 16; mask <<= 1)
#pragma unroll
    for (int t = 0; t < 16; ++t) ps[t] += __shfl_xor(ps[t], mask);
  if (fr == 0) {
#pragma unroll
    for (int mi = 0; mi < 4; ++mi)
#pragma unroll
      for (int q = 0; q < 4; ++q)
        red[mi * 16 + fg * 4 + q][wave] = ps[mi * 4 + q];
  }
  __syncthreads();
  if (tid < 64) {
    float s = 0.f;
#pragma unroll
    for (int w = 0; w < 8; ++w) s += red[tid][w];
    mrow[tid] = s * (1.f / 512.f);
  }
  __syncthreads();
  float mu[16];
#pragma unroll
  for (int mi = 0; mi < 4; ++mi)
#pragma unroll
    for (int q = 0; q < 4; ++q) mu[mi * 4 + q] = mrow[mi * 16 + fg * 4 + q];

  float ps2[16];
#pragma unroll
  for (int mi = 0; mi < 4; ++mi)
#pragma unroll
    for (int q = 0; q < 4; ++q) {
      const float m = mu[mi * 4 + q];
      float s = 0.f;
#pragma unroll
      for (int ni = 0; ni < 4; ++ni) {
        const float d = v[mi][ni][q] - m;
        s += d * d;
      }
      ps2[mi * 4 + q] = s;
    }
#pragma unroll
  for (int mask = 1; mask < 16; mask <<= 1)
#pragma unroll
    for (int t = 0; t < 16; ++t) ps2[t] += __shfl_xor(ps2[t], mask);
  if (fr == 0) {
#pragma unroll
    for (int mi = 0; mi < 4; ++mi)
#pragma unroll
      for (int q = 0; q < 4; ++q)
        red[mi * 16 + fg * 4 + q][wave] = ps2[mi * 4 + q];
  }
  __syncthreads();
  if (tid < 64) {
    float s = 0.f;
#pragma unroll
    for (int w = 0; w < 8; ++w) s += red[tid][w];
    rrow[tid] = rsqrtf(s * (1.f / 512.f) + EPS);
  }
  __syncthreads();

#pragma unroll
  for (int ni = 0; ni < 4; ++ni) {
    const int col = wave * 64 + ni * 16 + fr;
    const float gc = g[col], bc = bb[col];
#pragma unroll
    for (int mi = 0; mi < 4; ++mi)
#pragma unroll
      for (int q = 0; q < 4; ++q) {
        const int lrow = mi * 16 + fg * 4 + q;
        const float o = (v[mi][ni][q] - mu[mi * 4 + q]) * rrow[lrow] * gc + bc;
        outB[(size_t)(bm + lrow) * D + col] = __float2bfloat16(o);
      }
  }
}

// ---------------------------------------------------------------------------
// Small head GEMM (m97 structure, f32 out, N=64 valid). Proven.
// ---------------------------------------------------------------------------
template<int KSTEPS>
__global__ __launch_bounds__(256) void gemm_head_kernel(
    const __hip_bfloat16* __restrict__ A,
    const __hip_bfloat16* __restrict__ Wt,
    const float* __restrict__ bias,
    float* __restrict__ out1, int ostr1, int nvalid) {
  constexpr int K = KSTEPS * 32;
  __shared__ __hip_bfloat16 Als[2][128][32];
  __shared__ __hip_bfloat16 Bls[2][128][32];

  const int bm   = blockIdx.x * 128;
  const int bn   = blockIdx.y * 128;
  const int tid  = threadIdx.x;
  const int wave = tid >> 6;
  const int lane = tid & 63;
  const int wm   = (wave >> 1) * 64;
  const int wn   = (wave & 1) * 64;
  const int fr   = lane & 15;
  const int fg   = lane >> 4;

  const int srow = (lane >> 2);
  const int scol = (lane & 3) * 8;
  const __hip_bfloat16* gA0 = A  + (size_t)(bm + wave * 32 + srow) * K + scol;
  const __hip_bfloat16* gA1 = gA0 + 16 * K;
  const __hip_bfloat16* gB0 = Wt + (size_t)(bn + wave * 32 + srow) * K + scol;
  const __hip_bfloat16* gB1 = gB0 + 16 * K;

  f32x4 acc[4][4] = {};

  auto stage = [&](int buf, int ks) {
    const int ko = ks * 32;
    gload_lds16(gA0 + ko, &Als[buf][wave * 32][0]);
    gload_lds16(gA1 + ko, &Als[buf][wave * 32 + 16][0]);
    gload_lds16(gB0 + ko, &Bls[buf][wave * 32][0]);
    gload_lds16(gB1 + ko, &Bls[buf][wave * 32 + 16][0]);
  };

  stage(0, 0);
  int buf = 0;
  for (int ks = 0; ks < KSTEPS; ++ks) {
    __syncthreads();
    if (ks + 1 < KSTEPS) stage(buf ^ 1, ks + 1);
    short8b a[4], b[4];
#pragma unroll
    for (int mi = 0; mi < 4; ++mi)
      a[mi] = *reinterpret_cast<const short8b*>(&Als[buf][wm + mi * 16 + fr][fg * 8]);
#pragma unroll
    for (int ni = 0; ni < 4; ++ni)
      b[ni] = *reinterpret_cast<const short8b*>(&Bls[buf][wn + ni * 16 + fr][fg * 8]);
#pragma unroll
    for (int mi = 0; mi < 4; ++mi)
#pragma unroll
      for (int ni = 0; ni < 4; ++ni)
        acc[mi][ni] = __builtin_amdgcn_mfma_f32_16x16x32_bf16(a[mi], b[ni], acc[mi][ni], 0, 0, 0);
    buf ^= 1;
  }

#pragma unroll
  for (int ni = 0; ni < 4; ++ni) {
    const int col = bn + wn + ni * 16 + fr;
    if (col >= nvalid) continue;
    const float bv = bias ? bias[col] : 0.f;
#pragma unroll
    for (int mi = 0; mi < 4; ++mi) {
      const int row0 = bm + wm + mi * 16 + fg * 4;
#pragma unroll
      for (int q = 0; q < 4; ++q)
        out1[(size_t)(row0 + q) * ostr1 + col] = acc[mi][ni][q] + bv;
    }
  }
}

// ---------------------------------------------------------------------------
// Encoder GEMM+GELU+LN (K=96, BK=32). Proven.
// ---------------------------------------------------------------------------
__global__ __launch_bounds__(512) void gemm_ln_enc_kernel(
    const __hip_bfloat16* __restrict__ A,
    const __hip_bfloat16* __restrict__ Wt,
    const float* __restrict__ g, const float* __restrict__ bb,
    __hip_bfloat16* __restrict__ outB) {
  constexpr int K = 96;
  __shared__ __hip_bfloat16 Als[2][64][32];
  __shared__ __hip_bfloat16 Bls[2][512][32];
  __shared__ float red[64][8];
  __shared__ float mrow[64];
  __shared__ float rrow[64];

  const int bm   = blockIdx.x * 64;
  const int tid  = threadIdx.x;
  const int wave = tid >> 6;
  const int lane = tid & 63;
  const int fr   = lane & 15;
  const int fg   = lane >> 4;
  const int srow = lane >> 2;
  const int scol = (lane & 3) * 8;

  auto stage = [&](int buf, int ks) {
    const int ko = ks * 32;
    if (wave < 4)
      gload_lds16(A + (size_t)(bm + wave * 16 + srow) * K + ko + scol,
                  &Als[buf][wave * 16][0]);
#pragma unroll
    for (int c = 0; c < 4; ++c)
      gload_lds16(Wt + (size_t)(wave * 64 + c * 16 + srow) * K + ko + scol,
                  &Bls[buf][wave * 64 + c * 16][0]);
  };

  f32x4 acc[4][4] = {};
  stage(0, 0);
  int buf = 0;
  for (int ks = 0; ks < 3; ++ks) {
    __syncthreads();
    if (ks + 1 < 3) stage(buf ^ 1, ks + 1);
    short8b a[4], b[4];
#pragma unroll
    for (int mi = 0; mi < 4; ++mi)
      a[mi] = *reinterpret_cast<const short8b*>(&Als[buf][mi * 16 + fr][fg * 8]);
#pragma unroll
    for (int ni = 0; ni < 4; ++ni)
      b[ni] = *reinterpret_cast<const short8b*>(&Bls[buf][wave * 64 + ni * 16 + fr][fg * 8]);
#pragma unroll
    for (int mi = 0; mi < 4; ++mi)
#pragma unroll
      for (int ni = 0; ni < 4; ++ni)
        acc[mi][ni] = __builtin_amdgcn_mfma_f32_16x16x32_bf16(a[mi], b[ni], acc[mi][ni], 0, 0, 0);
    buf ^= 1;
  }

  float v[4][4][4];
#pragma unroll
  for (int mi = 0; mi < 4; ++mi)
#pragma unroll
    for (int q = 0; q < 4; ++q)
#pragma unroll
      for (int ni = 0; ni < 4; ++ni)
        v[mi][ni][q] = gelu_exact(acc[mi][ni][q]);

  float ps[16];
#pragma unroll
  for (int mi = 0; mi < 4; ++mi)
#pragma unroll
    for (int q = 0; q < 4; ++q)
      ps[mi * 4 + q] = v[mi][0][q] + v[mi][1][q] + v[mi][2][q] + v[mi][3][q];
#pragma unroll
  for (int mask = 1; mask < 16; mask <<= 1)
#pragma unroll
    for (int t = 0; t < 16; ++t) ps[t] += __shfl_xor(ps[t], mask);
  if (fr == 0)
#pragma unroll
    for (int mi = 0; mi < 4; ++mi)
#pragma unroll
      for (int q = 0; q < 4; ++q)
        red[mi * 16 + fg * 4 + q][wave] = ps[mi * 4 + q];
  __syncthreads();
  if (tid < 64) {
    float s = 0.f;
#pragma unroll
    for (int w = 0; w < 8; ++w) s += red[tid][w];
    mrow[tid] = s * (1.f / 512.f);
  }
  __syncthreads();
  float mu[16];
#pragma unroll
  for (int mi = 0; mi < 4; ++mi)
#pragma unroll
    for (int q = 0; q < 4; ++q) mu[mi * 4 + q] = mrow[mi * 16 + fg * 4 + q];
  float ps2[16];
#pragma unroll
  for (int mi = 0; mi < 4; ++mi)
#pragma unroll
    for (int q = 0; q < 4; ++q) {
      const float m = mu[mi * 4 + q];
      float s = 0.f;
#pragma unroll
      for (int ni = 0; ni < 4; ++ni) { const float d = v[mi][ni][q] - m; s += d * d; }
      ps2[mi * 4 + q] = s;
    }
#pragma unroll
  for (int mask = 1; mask < 16; mask <<= 1)
#pragma unroll
    for (int t = 0; t < 16; ++t) ps2[t] += __shfl_xor(ps2[t], mask);
  if (fr == 0)
#pragma unroll
    for (int mi = 0; mi < 4; ++mi)
#pragma unroll
      for (int q = 0; q < 4; ++q)
        red[mi * 16 + fg * 4 + q][wave] = ps2[mi * 4 + q];
  __syncthreads();
  if (tid < 64) {
    float s = 0.f;
#pragma unroll
    for (int w = 0; w < 8; ++w) s += red[tid][w];
    rrow[tid] = rsqrtf(s * (1.f / 512.f) + EPS);
  }
  __syncthreads();

#pragma unroll
  for (int ni = 0; ni < 4; ++ni) {
    const int col = wave * 64 + ni * 16 + fr;
    const float gc = g[col], bc = bb[col];
#pragma unroll
    for (int mi = 0; mi < 4; ++mi)
#pragma unroll
      for (int q = 0; q < 4; ++q) {
        const int lrow = mi * 16 + fg * 4 + q;
        const float o = (v[mi][ni][q] - mu[mi * 4 + q]) * rrow[lrow] * gc + bc;
        outB[(size_t)(bm + lrow) * D + col] = __float2bfloat16(o);
      }
  }
}

// ---------------------------------------------------------------------------
// MFMA attention core (unchanged).
// ---------------------------------------------------------------------------
__global__ __launch_bounds__(256) void attn_mfma_kernel(
    const __hip_bfloat16* __restrict__ qg, int qstr,
    const __hip_bfloat16* __restrict__ kg, int kstr,
    const __hip_bfloat16* __restrict__ vt,
    __hip_bfloat16* __restrict__ yg) {
  __shared__ __align__(16) char smem[33280];
  unsigned short* Qs  = (unsigned short*)smem;
  unsigned short* Ks  = (unsigned short*)(smem + 8192);
  float*          Ss  = (float*)smem;
  unsigned short* Vts = (unsigned short*)(smem + 16896);
  unsigned short* Ps  = (unsigned short*)(smem + 25088);

  const int tid  = threadIdx.x;
  const int bh   = blockIdx.x;
  const int bidx = bh >> 3, h = bh & 7;
  const size_t rbase = (size_t)bidx * 64;
  const int col0 = h * 64;

  const __hip_bfloat16* vtg = vt + (size_t)bh * 4096;
#pragma unroll
  for (int p = 0; p < 2; ++p) {
    const int idx = tid + p * 256;
    const int row = idx >> 3, c8 = (idx & 7) * 8;
    const int lb  = (row * 128 + c8 * 2) ^ ((row & 7) << 4);
    const uint4 vq = *reinterpret_cast<const uint4*>(qg + (rbase + row) * qstr + col0 + c8);
    const uint4 vk = *reinterpret_cast<const uint4*>(kg + (rbase + row) * kstr + col0 + c8);
    const uint4 vv = *reinterpret_cast<const uint4*>(vtg + idx * 8);
    *reinterpret_cast<uint4*>((char*)Qs  + lb) = vq;
    *reinterpret_cast<uint4*>((char*)Ks  + lb) = vk;
    *reinterpret_cast<uint4*>((char*)Vts + lb) = vv;
  }
  __syncthreads();

  const int wave = tid >> 6, lane = tid & 63;
  const int fr = lane & 15, fg = lane >> 4;
  const int wr = (wave >> 1) * 32, wc = (wave & 1) * 32;

  auto ldfrag = [&](const unsigned short* base, int row, int ks) -> short8b {
    const int byte = (row * 128 + ks * 64 + fg * 16) ^ ((row & 7) << 4);
    return *reinterpret_cast<const short8b*>((const char*)base + byte);
  };

  f32x4 acc[2][2] = {};
#pragma unroll
  for (int ks = 0; ks < 2; ++ks) {
    short8b a[2], b[2];
    a[0] = ldfrag(Qs, wr + fr, ks);
    a[1] = ldfrag(Qs, wr + 16 + fr, ks);
    b[0] = ldfrag(Ks, wc + fr, ks);
    b[1] = ldfrag(Ks, wc + 16 + fr, ks);
#pragma unroll
    for (int mi = 0; mi < 2; ++mi)
#pragma unroll
      for (int ni = 0; ni < 2; ++ni)
        acc[mi][ni] = __builtin_amdgcn_mfma_f32_16x16x32_bf16(a[mi], b[ni], acc[mi][ni], 0, 0, 0);
  }
  __syncthreads();

#pragma unroll
  for (int mi = 0; mi < 2; ++mi)
#pragma unroll
    for (int ni = 0; ni < 2; ++ni) {
      const int m2 = wc + ni * 16 + fr;
#pragma unroll
      for (int r = 0; r < 4; ++r) {
        const int n = wr + mi * 16 + fg * 4 + r;
        Ss[n * 66 + m2] = (m2 <= n) ? acc[mi][ni][r] * SCALE : -1e30f;
      }
    }
  __syncthreads();

  for (int n = wave * 16; n < wave * 16 + 16; ++n) {
    const float vv = Ss[n * 66 + lane];
    float mx = vv;
#pragma unroll
    for (int off = 1; off < 64; off <<= 1) mx = fmaxf(mx, __shfl_xor(mx, off));
    const float p = (lane <= n) ? __expf(vv - mx) : 0.f;
    float sum = p;
#pragma unroll
    for (int off = 1; off < 64; off <<= 1) sum += __shfl_xor(sum, off);
    const int byte = (n * 128 + lane * 2) ^ ((n & 7) << 4);
    *(unsigned short*)((char*)Ps + byte) = f2b_bits(p / sum);
  }
  __syncthreads();

  f32x4 acc2[2][2] = {};
#pragma unroll
  for (int ks = 0; ks < 2; ++ks) {
    short8b a[2], b[2];
    a[0] = ldfrag(Ps, wr + fr, ks);
    a[1] = ldfrag(Ps, wr + 16 + fr, ks);
    b[0] = ldfrag(Vts, wc + fr, ks);
    b[1] = ldfrag(Vts, wc + 16 + fr, ks);
#pragma unroll
    for (int mi = 0; mi < 2; ++mi)
#pragma unroll
      for (int ni = 0; ni < 2; ++ni)
        acc2[mi][ni] = __builtin_amdgcn_mfma_f32_16x16x32_bf16(a[mi], b[ni], acc2[mi][ni], 0, 0, 0);
  }
#pragma unroll
  for (int mi = 0; mi < 2; ++mi)
#pragma unroll
    for (int r = 0; r < 4; ++r) {
      const int n = wr + mi * 16 + fg * 4 + r;
      yg[(rbase + n) * 512 + col0 + wc + fr]      = __float2bfloat16(acc2[mi][0][r]);
      yg[(rbase + n) * 512 + col0 + wc + 16 + fr] = __float2bfloat16(acc2[mi][1][r]);
    }
}

// ---------------------------------------------------------------------------
// Prep kernels (unchanged).
// ---------------------------------------------------------------------------
__global__ __launch_bounds__(256) void wconv_all_kernel(
    const float* __restrict__ bwq, const float* __restrict__ bwk,
    const float* __restrict__ bwv, const float* __restrict__ bwp,
    const float* __restrict__ bw1, const float* __restrict__ bw2,
    const float* __restrict__ wh1,
    __hip_bfloat16* __restrict__ wSelf, __hip_bfloat16* __restrict__ wCq,
    __hip_bfloat16* __restrict__ wCkv, __hip_bfloat16* __restrict__ wTp,
    __hip_bfloat16* __restrict__ wTw1, __hip_bfloat16* __restrict__ wTw2,
    __hip_bfloat16* __restrict__ wTh1) {
  const size_t MAT = (size_t)D * D;
  const size_t SS = (size_t)1536 * 512, KV = (size_t)1024 * 512;
  const int z = blockIdx.z;
  const float* src;
  __hip_bfloat16* dst;
  if (z < 8)       { int i = z >> 1; src = bwq + (size_t)z * MAT;
                     dst = (z & 1) ? wCq + (size_t)i * MAT : wSelf + (size_t)i * SS; }
  else if (z < 16) { int zz = z - 8, i = zz >> 1; src = bwk + (size_t)zz * MAT;
                     dst = (zz & 1) ? wCkv + (size_t)i * KV
                                    : wSelf + (size_t)i * SS + 512 * 512; }
  else if (z < 24) { int zz = z - 16, i = zz >> 1; src = bwv + (size_t)zz * MAT;
                     dst = (zz & 1) ? wCkv + (size_t)i * KV + 512 * 512
                                    : wSelf + (size_t)i * SS + 1024 * 512; }
  else if (z < 32) { int zz = z - 24; src = bwp + (size_t)zz * MAT; dst = wTp + (size_t)zz * MAT; }
  else if (z < 36) { int zz = z - 32; src = bw1 + (size_t)zz * MAT; dst = wTw1 + (size_t)zz * MAT; }
  else if (z < 40) { int zz = z - 36; src = bw2 + (size_t)zz * MAT; dst = wTw2 + (size_t)zz * MAT; }
  else             { src = wh1; dst = wTh1; }

  __shared__ float tile[32][33];
  const int r0 = blockIdx.y * 32, c0 = blockIdx.x * 32;
  const int tr = threadIdx.x >> 5;
  const int tc = threadIdx.x & 31;
#pragma unroll
  for (int i = 0; i < 4; ++i)
    tile[tr + 8 * i][tc] = src[(size_t)(r0 + tr + 8 * i) * D + c0 + tc];
  __syncthreads();
#pragma unroll
  for (int i = 0; i < 4; ++i)
    dst[(size_t)(c0 + tr + 8 * i) * D + r0 + tc] = __float2bfloat16(tile[tc][tr + 8 * i]);
}

__global__ __launch_bounds__(256) void misc_prep_kernel(
    const float* __restrict__ w_ae, const float* __restrict__ wh2,
    const float* __restrict__ bbq, const float* __restrict__ bbk,
    const float* __restrict__ bbv, const float* __restrict__ action,
    const float* __restrict__ obs_rep,
    __hip_bfloat16* __restrict__ waeT, __hip_bfloat16* __restrict__ wh2p,
    float* __restrict__ selfb, float* __restrict__ ckvb,
    float* __restrict__ bqc, __hip_bfloat16* __restrict__ actb,
    __hip_bfloat16* __restrict__ orb) {
  constexpr int R0 = 512 * 96, R1 = 128 * 512, R2 = NBLK * 1536,
                R3 = NBLK * 1024, R4 = NBLK * 512, R5 = M * 96;
  constexpr int R6 = M * D / 4;
  constexpr int total = R0 + R1 + R2 + R3 + R4 + R5 + R6;
  for (int i = blockIdx.x * 256 + threadIdx.x; i < total; i += gridDim.x * 256) {
    int j = i;
    if (j < R0) {
      const int n = j / 96, k = j - n * 96;
      waeT[j] = (k < 65) ? __float2bfloat16(w_ae[(size_t)k * 512 + n]) : __float2bfloat16(0.f);
    } else if ((j -= R0) < R1) {
      const int n = j >> 9, k = j & 511;
      wh2p[j] = (n < 64) ? __float2bfloat16(wh2[(size_t)k * 64 + n]) : __float2bfloat16(0.f);
    } else if ((j -= R1) < R2) {
      const int blk = j / 1536, c = j - blk * 1536;
      const int seg = c >> 9, cc = c & 511;
      const float* s = (seg == 0) ? bbq : (seg == 1) ? bbk : bbv;
      selfb[j] = s[(size_t)(blk * 2) * 512 + cc];
    } else if ((j -= R2) < R3) {
      const int blk = j >> 10, c = j & 1023;
      ckvb[j] = (c < 512) ? bbk[(size_t)(blk * 2 + 1) * 512 + c]
                          : bbv[(size_t)(blk * 2 + 1) * 512 + (c - 512)];
    } else if ((j -= R3) < R4) {
      const int blk = j >> 9, c = j & 511;
      bqc[j] = bbq[(size_t)(blk * 2 + 1) * 512 + c];
    } else if ((j -= R4) < R5) {
      const int row = j / 96, k = j - row * 96;
      actb[j] = (k < 65) ? __float2bfloat16(action[(size_t)row * 65 + k]) : __float2bfloat16(0.f);
    } else {
      j -= R5;
      const float4 v = reinterpret_cast<const float4*>(obs_rep)[j];
      ushort4 o;
      o.x = f2b_bits(v.x); o.y = f2b_bits(v.y);
      o.z = f2b_bits(v.z); o.w = f2b_bits(v.w);
      reinterpret_cast<ushort4*>(orb)[j] = o;
    }
  }
}

}  // namespace

extern "C" void kernel_launch(void* const* d_in, const int* in_sizes, int n_in,
                              void* d_out, int out_size, void* d_ws, size_t ws_size,
                              hipStream_t stream) {
  const float* action  = (const float*)d_in[0];
  const float* obs_rep = (const float*)d_in[1];
  const float* w_ae    = (const float*)d_in[3];
  const float* ln0_g   = (const float*)d_in[4];
  const float* ln0_b   = (const float*)d_in[5];
  const float* bln_g   = (const float*)d_in[6];
  const float* bln_b   = (const float*)d_in[7];
  const float* bwq     = (const float*)d_in[8];
  const float* bwk     = (const float*)d_in[9];
  const float* bwv     = (const float*)d_in[10];
  const float* bwp     = (const float*)d_in[11];
  const float* bbq     = (const float*)d_in[12];
  const float* bbk     = (const float*)d_in[13];
  const float* bbv     = (const float*)d_in[14];
  const float* bbp     = (const float*)d_in[15];
  const float* bw1     = (const float*)d_in[16];
  const float* bb1     = (const float*)d_in[17];
  const float* bw2     = (const float*)d_in[18];
  const float* bb2     = (const float*)d_in[19];
  const float* wh1     = (const float*)d_in[20];
  const float* bh1     = (const float*)d_in[21];
  const float* lnh_g   = (const float*)d_in[22];
  const float* lnh_b   = (const float*)d_in[23];
  const float* wh2     = (const float*)d_in[24];
  const float* bh2     = (const float*)d_in[25];

  char* ws = (char*)d_ws;
  const size_t MAT = (size_t)D * D;
  const size_t szB = (size_t)M * D * 2;

  __hip_bfloat16* xb  = (__hip_bfloat16*)ws; ws += szB;
  __hip_bfloat16* hb  = (__hip_bfloat16*)ws; ws += szB;
  __hip_bfloat16* vtb = (__hip_bfloat16*)ws; ws += szB;
  __hip_bfloat16* orb = (__hip_bfloat16*)ws; ws += szB;
  __hip_bfloat16* qkb = (__hip_bfloat16*)ws; ws += 2 * szB;
  __hip_bfloat16* qcb = (__hip_bfloat16*)ws; ws += 4 * szB;
  __hip_bfloat16* kb  = (__hip_bfloat16*)ws; ws += szB;
  __hip_bfloat16* actb = (__hip_bfloat16*)ws; ws += (size_t)M * 96 * 2;
  __hip_bfloat16* wSelf = (__hip_bfloat16*)ws; ws += (size_t)NBLK * 1536 * 512 * 2;
  __hip_bfloat16* wCq   = (__hip_bfloat16*)ws; ws += (size_t)NBLK * 512 * 512 * 2;
  __hip_bfloat16* wCkv  = (__hip_bfloat16*)ws; ws += (size_t)NBLK * 1024 * 512 * 2;
  __hip_bfloat16* wTp   = (__hip_bfloat16*)ws; ws += 8 * MAT * 2;
  __hip_bfloat16* wTw1  = (__hip_bfloat16*)ws; ws += 4 * MAT * 2;
  __hip_bfloat16* wTw2  = (__hip_bfloat16*)ws; ws += 4 * MAT * 2;
  __hip_bfloat16* wTh1  = (__hip_bfloat16*)ws; ws += MAT * 2;
  __hip_bfloat16* wh2p  = (__hip_bfloat16*)ws; ws += 128 * 512 * 2;
  __hip_bfloat16* waeT  = (__hip_bfloat16*)ws; ws += 512 * 96 * 2;
  float* selfb         = (float*)ws;         ws += (size_t)NBLK * 1536 * 4;
  float* ckvb          = (float*)ws;         ws += (size_t)NBLK * 1024 * 4;
  float* bqc           = (float*)ws;         ws += (size_t)NBLK * 512 * 4;

  // ---- prep ----
  wconv_all_kernel<<<dim3(16, 16, 41), 256, 0, stream>>>(
      bwq, bwk, bwv, bwp, bw1, bw2, wh1,
      wSelf, wCq, wCkv, wTp, wTw1, wTw2, wTh1);
  misc_prep_kernel<<<2048, 256, 0, stream>>>(
      w_ae, wh2, bbq, bbk, bbv, action, obs_rep,
      waeT, wh2p, selfb, ckvb, bqc, actb, orb);

  const size_t SS = (size_t)1536 * 512;
  const size_t KV = (size_t)1024 * 512;
  const int lnGrid = M / 64;

  // ---- encoder ----
  gemm_ln_enc_kernel<<<lnGrid, 512, 0, stream>>>(actb, waeT, ln0_g, ln0_b, xb);

  // ---- batched cross-attention Q for all 4 blocks ----
  gemm_dp2b_kernel<false, NEVER><<<M / 256 * 8, 512, 0, stream>>>(
      orb, wCq, bqc, qcb, 2048, nullptr, 8);

  for (int i = 0; i < NBLK; ++i) {
    const float* g0 = bln_g + (size_t)(i * 3 + 0) * D;
    const float* b0 = bln_b + (size_t)(i * 3 + 0) * D;
    const float* g1 = bln_g + (size_t)(i * 3 + 1) * D;
    const float* b1 = bln_b + (size_t)(i * 3 + 1) * D;
    const float* g2 = bln_g + (size_t)(i * 3 + 2) * D;
    const float* b2 = bln_b + (size_t)(i * 3 + 2) * D;

    // sublayer 1: self-attention
    gemm_dp2b_kernel<false, 1024><<<M / 256 * 6, 512, 0, stream>>>(
        xb, wSelf + (size_t)i * SS, selfb + (size_t)i * 1536, qkb, 1024, vtb, 6);
    attn_mfma_kernel<<<B * H, 256, 0, stream>>>(qkb, 1024, qkb + 512, 1024, vtb, hb);
    gemm_ln64_kernel<false, true><<<lnGrid, 512, 0, stream>>>(
        hb, wTp + (size_t)(i * 2) * MAT, bbp + (size_t)(i * 2) * D, xb, g0, b0, xb);

    // sublayer 2: cross-attention
    gemm_dp2b_kernel<false, 512><<<M / 256 * 4, 512, 0, stream>>>(
        xb, wCkv + (size_t)i * KV, ckvb + (size_t)i * 1024, kb, 512, vtb, 4);
    attn_mfma_kernel<<<B * H, 256, 0, stream>>>(
        qcb + (size_t)i * 512, 2048, kb, 512, vtb, hb);
    gemm_ln64_kernel<false, true><<<lnGrid, 512, 0, stream>>>(
        hb, wTp + (size_t)(i * 2 + 1) * MAT, bbp + (size_t)(i * 2 + 1) * D,
        orb, g1, b1, xb);

    // sublayer 3: MLP (w1 keeps the proven 128x256 dp kernel)
    gemm_dp_kernel<true, NEVER><<<M / 128 * 2, 512, 0, stream>>>(
        xb, wTw1 + (size_t)i * MAT, bb1 + (size_t)i * D, hb, 512, nullptr, 2);
    gemm_ln64_kernel<false, true><<<lnGrid, 512, 0, stream>>>(
        hb, wTw2 + (size_t)i * MAT, bb2 + (size_t)i * D, xb, g2, b2, xb);
  }

  // ---- head: GEMM+GELU+LN then small GEMM ----
  gemm_ln64_kernel<true, false><<<lnGrid, 512, 0, stream>>>(
      xb, wTh1, bh1, nullptr, lnh_g, lnh_b, hb);
  gemm_head_kernel<16><<<dim3(M / 128, 1), 256, 0, stream>>>(
      hb, wh2p, bh2, (float*)d_out, 64, 64);
}

// Round 11
// 986.122 us; speedup vs baseline: 1.0598x; 1.0598x over previous
//
#include <hip/hip_runtime.h>
#include <hip/hip_bf16.h>
#include <math.h>

namespace {

constexpr int B  = 256;
constexpr int N  = 64;
constexpr int D  = 512;
constexpr int H  = 8;
constexpr int NBLK = 4;
constexpr int M  = B * N;
constexpr float EPS = 1e-5f;
constexpr float SCALE = 0.125f;
constexpr int NEVER = 1 << 20;

typedef __attribute__((ext_vector_type(8))) short short8b;
typedef __attribute__((ext_vector_type(4))) float f32x4;

__device__ __forceinline__ float gelu_exact(float x) {
  return 0.5f * x * (1.0f + erff(x * 0.70710678118654752440f));
}

__device__ __forceinline__ unsigned short f2b_bits(float f) {
  __hip_bfloat16 h = __float2bfloat16(f);
  return *reinterpret_cast<unsigned short*>(&h);
}

#define GLOBAL_AS __attribute__((address_space(1)))
#define LDS_AS    __attribute__((address_space(3)))

__device__ __forceinline__ void gload_lds16(const void* g, void* l) {
  __builtin_amdgcn_global_load_lds((const GLOBAL_AS void*)g, (LDS_AS void*)l, 16, 0, 0);
}

__device__ __forceinline__ void barrier_pinned() {
  __builtin_amdgcn_sched_barrier(0);
  __builtin_amdgcn_s_barrier();
  __builtin_amdgcn_sched_barrier(0);
}

// ---------------------------------------------------------------------------
// Deep-pipelined bf16 MFMA GEMM, 128x256 tile, BK=64, 3 LDS buffers,
// counted vmcnt(6) (proven: 0 bank conflicts, MfmaUtil ~25%).
// ---------------------------------------------------------------------------
template<bool GELU, int SPLIT>
__global__ __launch_bounds__(512, 2) void gemm_dp_kernel(
    const __hip_bfloat16* __restrict__ A,
    const __hip_bfloat16* __restrict__ Wt,
    const float* __restrict__ bias,
    __hip_bfloat16* __restrict__ out1, int ostr1,
    __hip_bfloat16* __restrict__ vt, int gy) {
  constexpr int K = 512;
  constexpr int NT = 8;
  __shared__ __hip_bfloat16 Als[3][128][64];
  __shared__ __hip_bfloat16 Bls[3][256][64];

  const int nwg = gridDim.x;
  const int hw  = blockIdx.x;
  const int cpx = nwg >> 3;
  const int lg  = (hw & 7) * cpx + (hw >> 3);
  const int bm  = (lg / gy) * 128;
  const int bn  = (lg % gy) * 256;

  const int tid  = threadIdx.x;
  const int wave = tid >> 6;
  const int lane = tid & 63;
  const int wm   = (wave >> 2) * 64;
  const int wn   = (wave & 3) * 64;
  const int fr   = lane & 15;
  const int fg   = lane >> 4;

  const int srow  = tid >> 3;
  const int sslot = (tid & 7) ^ (srow & 7);
  const __hip_bfloat16* gA = A  + (size_t)(bm + srow) * K + sslot * 8;
  const __hip_bfloat16* gB = Wt + (size_t)(bn + srow) * K + sslot * 8;

  auto STAGE = [&](int buf, int kt) {
    const int ko = kt * 64;
    char* la = (char*)&Als[buf][0][0] + wave * 1024;
    char* lb = (char*)&Bls[buf][0][0] + wave * 1024;
    gload_lds16(gA + ko,           la);
    gload_lds16(gA + 64 * K + ko,  la + 8192);
    gload_lds16(gB + ko,           lb);
    gload_lds16(gB + 64 * K + ko,  lb + 8192);
    gload_lds16(gB + 128 * K + ko, lb + 16384);
    gload_lds16(gB + 192 * K + ko, lb + 24576);
  };

  auto lda = [&](int buf, int mi, int ks) -> short8b {
    const int row  = wm + mi * 16 + fr;
    const int byte = row * 128 + (((ks << 2) | fg) ^ (fr & 7)) * 16;
    return *reinterpret_cast<const short8b*>((const char*)&Als[buf][0][0] + byte);
  };
  auto ldb = [&](int buf, int ni, int ks) -> short8b {
    const int row  = wn + ni * 16 + fr;
    const int byte = row * 128 + (((ks << 2) | fg) ^ (fr & 7)) * 16;
    return *reinterpret_cast<const short8b*>((const char*)&Bls[buf][0][0] + byte);
  };

  STAGE(0, 0);
  STAGE(1, 1);
  asm volatile("s_waitcnt vmcnt(6)" ::: "memory");
  barrier_pinned();

  f32x4 acc[4][4] = {};
  for (int t = 0; t < NT; ++t) {
    const int cur = t % 3;
    if (t + 2 < NT) STAGE((t + 2) % 3, t + 2);

    short8b a0[4], b0[4], a1[4], b1[4];
#pragma unroll
    for (int mi = 0; mi < 4; ++mi) a0[mi] = lda(cur, mi, 0);
#pragma unroll
    for (int ni = 0; ni < 4; ++ni) b0[ni] = ldb(cur, ni, 0);
#pragma unroll
    for (int mi = 0; mi < 4; ++mi) a1[mi] = lda(cur, mi, 1);
#pragma unroll
    for (int ni = 0; ni < 4; ++ni) b1[ni] = ldb(cur, ni, 1);

    __builtin_amdgcn_s_setprio(1);
#pragma unroll
    for (int mi = 0; mi < 4; ++mi)
#pragma unroll
      for (int ni = 0; ni < 4; ++ni)
        acc[mi][ni] = __builtin_amdgcn_mfma_f32_16x16x32_bf16(a0[mi], b0[ni], acc[mi][ni], 0, 0, 0);
#pragma unroll
    for (int mi = 0; mi < 4; ++mi)
#pragma unroll
      for (int ni = 0; ni < 4; ++ni)
        acc[mi][ni] = __builtin_amdgcn_mfma_f32_16x16x32_bf16(a1[mi], b1[ni], acc[mi][ni], 0, 0, 0);
    __builtin_amdgcn_s_setprio(0);

    if (t + 2 < NT) {
      asm volatile("s_waitcnt vmcnt(6)" ::: "memory");
    } else {
      asm volatile("s_waitcnt vmcnt(0)" ::: "memory");
    }
    barrier_pinned();
  }

#pragma unroll
  for (int ni = 0; ni < 4; ++ni) {
    const int col = bn + wn + ni * 16 + fr;
    const float bv = bias ? bias[col] : 0.f;
#pragma unroll
    for (int mi = 0; mi < 4; ++mi) {
      const int row0 = bm + wm + mi * 16 + fg * 4;
      if (col >= SPLIT) {
        const int vcol = col - SPLIT;
        ushort4 o;
        o.x = f2b_bits(acc[mi][ni][0] + bv);
        o.y = f2b_bits(acc[mi][ni][1] + bv);
        o.z = f2b_bits(acc[mi][ni][2] + bv);
        o.w = f2b_bits(acc[mi][ni][3] + bv);
        const int b8 = row0 >> 6, nl = row0 & 63;
        const int hh = vcol >> 6, dl = vcol & 63;
        *reinterpret_cast<ushort4*>(vt +
            ((size_t)(b8 * 8 + hh) * 4096 + dl * 64 + nl)) = o;
      } else {
#pragma unroll
        for (int q = 0; q < 4; ++q) {
          float v = acc[mi][ni][q] + bv;
          if (GELU) v = gelu_exact(v);
          out1[(size_t)(row0 + q) * ostr1 + col] = __float2bfloat16(v);
        }
      }
    }
  }
}

// ---------------------------------------------------------------------------
// GEMM + bias (+GELU) + bf16 residual + LN, BK=64 swizzled (K=512). Proven.
// ---------------------------------------------------------------------------
template<bool GELU_PRE, bool RES>
__global__ __launch_bounds__(512) void gemm_ln64_kernel(
    const __hip_bfloat16* __restrict__ A,
    const __hip_bfloat16* __restrict__ Wt,
    const float* __restrict__ bias,
    const __hip_bfloat16* __restrict__ resb,
    const float* __restrict__ g, const float* __restrict__ bb,
    __hip_bfloat16* __restrict__ outB) {
  __shared__ __hip_bfloat16 Als[2][64][64];
  __shared__ __hip_bfloat16 Bls[2][512][64];
  __shared__ float red[64][8];
  __shared__ float mrow[64];
  __shared__ float rrow[64];

  const int bm   = blockIdx.x * 64;
  const int tid  = threadIdx.x;
  const int wave = tid >> 6;
  const int lane = tid & 63;
  const int fr   = lane & 15;
  const int fg   = lane >> 4;

  const int srow  = tid >> 3;
  const int sslot = (tid & 7) ^ (srow & 7);

  auto stage = [&](int buf, int kt) {
    const int ko = kt * 64;
    gload_lds16(A + (size_t)(bm + srow) * 512 + ko + sslot * 8,
                (char*)&Als[buf][0][0] + wave * 1024);
#pragma unroll
    for (int j = 0; j < 8; ++j) {
      const int row = j * 64 + srow;
      const int sl  = (tid & 7) ^ (row & 7);
      gload_lds16(Wt + (size_t)row * 512 + ko + sl * 8,
                  (char*)&Bls[buf][0][0] + j * 8192 + wave * 1024);
    }
  };

  auto lda = [&](int buf, int mi, int ks) -> short8b {
    const int row  = mi * 16 + fr;
    const int byte = row * 128 + (((ks << 2) | fg) ^ (row & 7)) * 16;
    return *reinterpret_cast<const short8b*>((const char*)&Als[buf][0][0] + byte);
  };
  auto ldb = [&](int buf, int ni, int ks) -> short8b {
    const int row  = wave * 64 + ni * 16 + fr;
    const int byte = row * 128 + (((ks << 2) | fg) ^ (row & 7)) * 16;
    return *reinterpret_cast<const short8b*>((const char*)&Bls[buf][0][0] + byte);
  };

  f32x4 acc[4][4] = {};
  stage(0, 0);
  int buf = 0;
  for (int kt = 0; kt < 8; ++kt) {
    __syncthreads();
    if (kt + 1 < 8) stage(buf ^ 1, kt + 1);
    short8b a0[4], b0[4], a1[4], b1[4];
#pragma unroll
    for (int mi = 0; mi < 4; ++mi) a0[mi] = lda(buf, mi, 0);
#pragma unroll
    for (int ni = 0; ni < 4; ++ni) b0[ni] = ldb(buf, ni, 0);
#pragma unroll
    for (int mi = 0; mi < 4; ++mi) a1[mi] = lda(buf, mi, 1);
#pragma unroll
    for (int ni = 0; ni < 4; ++ni) b1[ni] = ldb(buf, ni, 1);
    __builtin_amdgcn_s_setprio(1);
#pragma unroll
    for (int mi = 0; mi < 4; ++mi)
#pragma unroll
      for (int ni = 0; ni < 4; ++ni)
        acc[mi][ni] = __builtin_amdgcn_mfma_f32_16x16x32_bf16(a0[mi], b0[ni], acc[mi][ni], 0, 0, 0);
#pragma unroll
    for (int mi = 0; mi < 4; ++mi)
#pragma unroll
      for (int ni = 0; ni < 4; ++ni)
        acc[mi][ni] = __builtin_amdgcn_mfma_f32_16x16x32_bf16(a1[mi], b1[ni], acc[mi][ni], 0, 0, 0);
    __builtin_amdgcn_s_setprio(0);
    buf ^= 1;
  }

  float v[4][4][4];
  float bvc[4];
#pragma unroll
  for (int ni = 0; ni < 4; ++ni)
    bvc[ni] = bias ? bias[wave * 64 + ni * 16 + fr] : 0.f;
#pragma unroll
  for (int mi = 0; mi < 4; ++mi)
#pragma unroll
    for (int q = 0; q < 4; ++q) {
      const int row = bm + mi * 16 + fg * 4 + q;
#pragma unroll
      for (int ni = 0; ni < 4; ++ni) {
        float t = acc[mi][ni][q] + bvc[ni];
        if (GELU_PRE) t = gelu_exact(t);
        if (RES)
          t += __bfloat162float(resb[(size_t)row * D + wave * 64 + ni * 16 + fr]);
        v[mi][ni][q] = t;
      }
    }

  float ps[16];
#pragma unroll
  for (int mi = 0; mi < 4; ++mi)
#pragma unroll
    for (int q = 0; q < 4; ++q)
      ps[mi * 4 + q] = v[mi][0][q] + v[mi][1][q] + v[mi][2][q] + v[mi][3][q];
#pragma unroll
  for (int mask = 1; mask < 16; mask <<= 1)
#pragma unroll
    for (int t = 0; t < 16; ++t) ps[t] += __shfl_xor(ps[t], mask);
  if (fr == 0) {
#pragma unroll
    for (int mi = 0; mi < 4; ++mi)
#pragma unroll
      for (int q = 0; q < 4; ++q)
        red[mi * 16 + fg * 4 + q][wave] = ps[mi * 4 + q];
  }
  __syncthreads();
  if (tid < 64) {
    float s = 0.f;
#pragma unroll
    for (int w = 0; w < 8; ++w) s += red[tid][w];
    mrow[tid] = s * (1.f / 512.f);
  }
  __syncthreads();
  float mu[16];
#pragma unroll
  for (int mi = 0; mi < 4; ++mi)
#pragma unroll
    for (int q = 0; q < 4; ++q) mu[mi * 4 + q] = mrow[mi * 16 + fg * 4 + q];

  float ps2[16];
#pragma unroll
  for (int mi = 0; mi < 4; ++mi)
#pragma unroll
    for (int q = 0; q < 4; ++q) {
      const float m = mu[mi * 4 + q];
      float s = 0.f;
#pragma unroll
      for (int ni = 0; ni < 4; ++ni) {
        const float d = v[mi][ni][q] - m;
        s += d * d;
      }
      ps2[mi * 4 + q] = s;
    }
#pragma unroll
  for (int mask = 1; mask < 16; mask <<= 1)
#pragma unroll
    for (int t = 0; t < 16; ++t) ps2[t] += __shfl_xor(ps2[t], mask);
  if (fr == 0) {
#pragma unroll
    for (int mi = 0; mi < 4; ++mi)
#pragma unroll
      for (int q = 0; q < 4; ++q)
        red[mi * 16 + fg * 4 + q][wave] = ps2[mi * 4 + q];
  }
  __syncthreads();
  if (tid < 64) {
    float s = 0.f;
#pragma unroll
    for (int w = 0; w < 8; ++w) s += red[tid][w];
    rrow[tid] = rsqrtf(s * (1.f / 512.f) + EPS);
  }
  __syncthreads();

#pragma unroll
  for (int ni = 0; ni < 4; ++ni) {
    const int col = wave * 64 + ni * 16 + fr;
    const float gc = g[col], bc = bb[col];
#pragma unroll
    for (int mi = 0; mi < 4; ++mi)
#pragma unroll
      for (int q = 0; q < 4; ++q) {
        const int lrow = mi * 16 + fg * 4 + q;
        const float o = (v[mi][ni][q] - mu[mi * 4 + q]) * rrow[lrow] * gc + bc;
        outB[(size_t)(bm + lrow) * D + col] = __float2bfloat16(o);
      }
  }
}

// ---------------------------------------------------------------------------
// Small head GEMM (m97 structure, f32 out, N=64 valid). Proven.
// ---------------------------------------------------------------------------
template<int KSTEPS>
__global__ __launch_bounds__(256) void gemm_head_kernel(
    const __hip_bfloat16* __restrict__ A,
    const __hip_bfloat16* __restrict__ Wt,
    const float* __restrict__ bias,
    float* __restrict__ out1, int ostr1, int nvalid) {
  constexpr int K = KSTEPS * 32;
  __shared__ __hip_bfloat16 Als[2][128][32];
  __shared__ __hip_bfloat16 Bls[2][128][32];

  const int bm   = blockIdx.x * 128;
  const int bn   = blockIdx.y * 128;
  const int tid  = threadIdx.x;
  const int wave = tid >> 6;
  const int lane = tid & 63;
  const int wm   = (wave >> 1) * 64;
  const int wn   = (wave & 1) * 64;
  const int fr   = lane & 15;
  const int fg   = lane >> 4;

  const int srow = (lane >> 2);
  const int scol = (lane & 3) * 8;
  const __hip_bfloat16* gA0 = A  + (size_t)(bm + wave * 32 + srow) * K + scol;
  const __hip_bfloat16* gA1 = gA0 + 16 * K;
  const __hip_bfloat16* gB0 = Wt + (size_t)(bn + wave * 32 + srow) * K + scol;
  const __hip_bfloat16* gB1 = gB0 + 16 * K;

  f32x4 acc[4][4] = {};

  auto stage = [&](int buf, int ks) {
    const int ko = ks * 32;
    gload_lds16(gA0 + ko, &Als[buf][wave * 32][0]);
    gload_lds16(gA1 + ko, &Als[buf][wave * 32 + 16][0]);
    gload_lds16(gB0 + ko, &Bls[buf][wave * 32][0]);
    gload_lds16(gB1 + ko, &Bls[buf][wave * 32 + 16][0]);
  };

  stage(0, 0);
  int buf = 0;
  for (int ks = 0; ks < KSTEPS; ++ks) {
    __syncthreads();
    if (ks + 1 < KSTEPS) stage(buf ^ 1, ks + 1);
    short8b a[4], b[4];
#pragma unroll
    for (int mi = 0; mi < 4; ++mi)
      a[mi] = *reinterpret_cast<const short8b*>(&Als[buf][wm + mi * 16 + fr][fg * 8]);
#pragma unroll
    for (int ni = 0; ni < 4; ++ni)
      b[ni] = *reinterpret_cast<const short8b*>(&Bls[buf][wn + ni * 16 + fr][fg * 8]);
#pragma unroll
    for (int mi = 0; mi < 4; ++mi)
#pragma unroll
      for (int ni = 0; ni < 4; ++ni)
        acc[mi][ni] = __builtin_amdgcn_mfma_f32_16x16x32_bf16(a[mi], b[ni], acc[mi][ni], 0, 0, 0);
    buf ^= 1;
  }

#pragma unroll
  for (int ni = 0; ni < 4; ++ni) {
    const int col = bn + wn + ni * 16 + fr;
    if (col >= nvalid) continue;
    const float bv = bias ? bias[col] : 0.f;
#pragma unroll
    for (int mi = 0; mi < 4; ++mi) {
      const int row0 = bm + wm + mi * 16 + fg * 4;
#pragma unroll
      for (int q = 0; q < 4; ++q)
        out1[(size_t)(row0 + q) * ostr1 + col] = acc[mi][ni][q] + bv;
    }
  }
}

// ---------------------------------------------------------------------------
// Encoder GEMM+GELU+LN (K=96, BK=32). Proven.
// ---------------------------------------------------------------------------
__global__ __launch_bounds__(512) void gemm_ln_enc_kernel(
    const __hip_bfloat16* __restrict__ A,
    const __hip_bfloat16* __restrict__ Wt,
    const float* __restrict__ g, const float* __restrict__ bb,
    __hip_bfloat16* __restrict__ outB) {
  constexpr int K = 96;
  __shared__ __hip_bfloat16 Als[2][64][32];
  __shared__ __hip_bfloat16 Bls[2][512][32];
  __shared__ float red[64][8];
  __shared__ float mrow[64];
  __shared__ float rrow[64];

  const int bm   = blockIdx.x * 64;
  const int tid  = threadIdx.x;
  const int wave = tid >> 6;
  const int lane = tid & 63;
  const int fr   = lane & 15;
  const int fg   = lane >> 4;
  const int srow = lane >> 2;
  const int scol = (lane & 3) * 8;

  auto stage = [&](int buf, int ks) {
    const int ko = ks * 32;
    if (wave < 4)
      gload_lds16(A + (size_t)(bm + wave * 16 + srow) * K + ko + scol,
                  &Als[buf][wave * 16][0]);
#pragma unroll
    for (int c = 0; c < 4; ++c)
      gload_lds16(Wt + (size_t)(wave * 64 + c * 16 + srow) * K + ko + scol,
                  &Bls[buf][wave * 64 + c * 16][0]);
  };

  f32x4 acc[4][4] = {};
  stage(0, 0);
  int buf = 0;
  for (int ks = 0; ks < 3; ++ks) {
    __syncthreads();
    if (ks + 1 < 3) stage(buf ^ 1, ks + 1);
    short8b a[4], b[4];
#pragma unroll
    for (int mi = 0; mi < 4; ++mi)
      a[mi] = *reinterpret_cast<const short8b*>(&Als[buf][mi * 16 + fr][fg * 8]);
#pragma unroll
    for (int ni = 0; ni < 4; ++ni)
      b[ni] = *reinterpret_cast<const short8b*>(&Bls[buf][wave * 64 + ni * 16 + fr][fg * 8]);
#pragma unroll
    for (int mi = 0; mi < 4; ++mi)
#pragma unroll
      for (int ni = 0; ni < 4; ++ni)
        acc[mi][ni] = __builtin_amdgcn_mfma_f32_16x16x32_bf16(a[mi], b[ni], acc[mi][ni], 0, 0, 0);
    buf ^= 1;
  }

  float v[4][4][4];
#pragma unroll
  for (int mi = 0; mi < 4; ++mi)
#pragma unroll
    for (int q = 0; q < 4; ++q)
#pragma unroll
      for (int ni = 0; ni < 4; ++ni)
        v[mi][ni][q] = gelu_exact(acc[mi][ni][q]);

  float ps[16];
#pragma unroll
  for (int mi = 0; mi < 4; ++mi)
#pragma unroll
    for (int q = 0; q < 4; ++q)
      ps[mi * 4 + q] = v[mi][0][q] + v[mi][1][q] + v[mi][2][q] + v[mi][3][q];
#pragma unroll
  for (int mask = 1; mask < 16; mask <<= 1)
#pragma unroll
    for (int t = 0; t < 16; ++t) ps[t] += __shfl_xor(ps[t], mask);
  if (fr == 0)
#pragma unroll
    for (int mi = 0; mi < 4; ++mi)
#pragma unroll
      for (int q = 0; q < 4; ++q)
        red[mi * 16 + fg * 4 + q][wave] = ps[mi * 4 + q];
  __syncthreads();
  if (tid < 64) {
    float s = 0.f;
#pragma unroll
    for (int w = 0; w < 8; ++w) s += red[tid][w];
    mrow[tid] = s * (1.f / 512.f);
  }
  __syncthreads();
  float mu[16];
#pragma unroll
  for (int mi = 0; mi < 4; ++mi)
#pragma unroll
    for (int q = 0; q < 4; ++q) mu[mi * 4 + q] = mrow[mi * 16 + fg * 4 + q];
  float ps2[16];
#pragma unroll
  for (int mi = 0; mi < 4; ++mi)
#pragma unroll
    for (int q = 0; q < 4; ++q) {
      const float m = mu[mi * 4 + q];
      float s = 0.f;
#pragma unroll
      for (int ni = 0; ni < 4; ++ni) { const float d = v[mi][ni][q] - m; s += d * d; }
      ps2[mi * 4 + q] = s;
    }
#pragma unroll
  for (int mask = 1; mask < 16; mask <<= 1)
#pragma unroll
    for (int t = 0; t < 16; ++t) ps2[t] += __shfl_xor(ps2[t], mask);
  if (fr == 0)
#pragma unroll
    for (int mi = 0; mi < 4; ++mi)
#pragma unroll
      for (int q = 0; q < 4; ++q)
        red[mi * 16 + fg * 4 + q][wave] = ps2[mi * 4 + q];
  __syncthreads();
  if (tid < 64) {
    float s = 0.f;
#pragma unroll
    for (int w = 0; w < 8; ++w) s += red[tid][w];
    rrow[tid] = rsqrtf(s * (1.f / 512.f) + EPS);
  }
  __syncthreads();

#pragma unroll
  for (int ni = 0; ni < 4; ++ni) {
    const int col = wave * 64 + ni * 16 + fr;
    const float gc = g[col], bc = bb[col];
#pragma unroll
    for (int mi = 0; mi < 4; ++mi)
#pragma unroll
      for (int q = 0; q < 4; ++q) {
        const int lrow = mi * 16 + fg * 4 + q;
        const float o = (v[mi][ni][q] - mu[mi * 4 + q]) * rrow[lrow] * gc + bc;
        outB[(size_t)(bm + lrow) * D + col] = __float2bfloat16(o);
      }
  }
}

// ---------------------------------------------------------------------------
// MFMA attention core (proven).
// ---------------------------------------------------------------------------
__global__ __launch_bounds__(256) void attn_mfma_kernel(
    const __hip_bfloat16* __restrict__ qg, int qstr,
    const __hip_bfloat16* __restrict__ kg, int kstr,
    const __hip_bfloat16* __restrict__ vt,
    __hip_bfloat16* __restrict__ yg) {
  __shared__ __align__(16) char smem[33280];
  unsigned short* Qs  = (unsigned short*)smem;
  unsigned short* Ks  = (unsigned short*)(smem + 8192);
  float*          Ss  = (float*)smem;
  unsigned short* Vts = (unsigned short*)(smem + 16896);
  unsigned short* Ps  = (unsigned short*)(smem + 25088);

  const int tid  = threadIdx.x;
  const int bh   = blockIdx.x;
  const int bidx = bh >> 3, h = bh & 7;
  const size_t rbase = (size_t)bidx * 64;
  const int col0 = h * 64;

  const __hip_bfloat16* vtg = vt + (size_t)bh * 4096;
#pragma unroll
  for (int p = 0; p < 2; ++p) {
    const int idx = tid + p * 256;
    const int row = idx >> 3, c8 = (idx & 7) * 8;
    const int lb  = (row * 128 + c8 * 2) ^ ((row & 7) << 4);
    const uint4 vq = *reinterpret_cast<const uint4*>(qg + (rbase + row) * qstr + col0 + c8);
    const uint4 vk = *reinterpret_cast<const uint4*>(kg + (rbase + row) * kstr + col0 + c8);
    const uint4 vv = *reinterpret_cast<const uint4*>(vtg + idx * 8);
    *reinterpret_cast<uint4*>((char*)Qs  + lb) = vq;
    *reinterpret_cast<uint4*>((char*)Ks  + lb) = vk;
    *reinterpret_cast<uint4*>((char*)Vts + lb) = vv;
  }
  __syncthreads();

  const int wave = tid >> 6, lane = tid & 63;
  const int fr = lane & 15, fg = lane >> 4;
  const int wr = (wave >> 1) * 32, wc = (wave & 1) * 32;

  auto ldfrag = [&](const unsigned short* base, int row, int ks) -> short8b {
    const int byte = (row * 128 + ks * 64 + fg * 16) ^ ((row & 7) << 4);
    return *reinterpret_cast<const short8b*>((const char*)base + byte);
  };

  f32x4 acc[2][2] = {};
#pragma unroll
  for (int ks = 0; ks < 2; ++ks) {
    short8b a[2], b[2];
    a[0] = ldfrag(Qs, wr + fr, ks);
    a[1] = ldfrag(Qs, wr + 16 + fr, ks);
    b[0] = ldfrag(Ks, wc + fr, ks);
    b[1] = ldfrag(Ks, wc + 16 + fr, ks);
#pragma unroll
    for (int mi = 0; mi < 2; ++mi)
#pragma unroll
      for (int ni = 0; ni < 2; ++ni)
        acc[mi][ni] = __builtin_amdgcn_mfma_f32_16x16x32_bf16(a[mi], b[ni], acc[mi][ni], 0, 0, 0);
  }
  __syncthreads();

#pragma unroll
  for (int mi = 0; mi < 2; ++mi)
#pragma unroll
    for (int ni = 0; ni < 2; ++ni) {
      const int m2 = wc + ni * 16 + fr;
#pragma unroll
      for (int r = 0; r < 4; ++r) {
        const int n = wr + mi * 16 + fg * 4 + r;
        Ss[n * 66 + m2] = (m2 <= n) ? acc[mi][ni][r] * SCALE : -1e30f;
      }
    }
  __syncthreads();

  for (int n = wave * 16; n < wave * 16 + 16; ++n) {
    const float vv = Ss[n * 66 + lane];
    float mx = vv;
#pragma unroll
    for (int off = 1; off < 64; off <<= 1) mx = fmaxf(mx, __shfl_xor(mx, off));
    const float p = (lane <= n) ? __expf(vv - mx) : 0.f;
    float sum = p;
#pragma unroll
    for (int off = 1; off < 64; off <<= 1) sum += __shfl_xor(sum, off);
    const int byte = (n * 128 + lane * 2) ^ ((n & 7) << 4);
    *(unsigned short*)((char*)Ps + byte) = f2b_bits(p / sum);
  }
  __syncthreads();

  f32x4 acc2[2][2] = {};
#pragma unroll
  for (int ks = 0; ks < 2; ++ks) {
    short8b a[2], b[2];
    a[0] = ldfrag(Ps, wr + fr, ks);
    a[1] = ldfrag(Ps, wr + 16 + fr, ks);
    b[0] = ldfrag(Vts, wc + fr, ks);
    b[1] = ldfrag(Vts, wc + 16 + fr, ks);
#pragma unroll
    for (int mi = 0; mi < 2; ++mi)
#pragma unroll
      for (int ni = 0; ni < 2; ++ni)
        acc2[mi][ni] = __builtin_amdgcn_mfma_f32_16x16x32_bf16(a[mi], b[ni], acc2[mi][ni], 0, 0, 0);
  }
#pragma unroll
  for (int mi = 0; mi < 2; ++mi)
#pragma unroll
    for (int r = 0; r < 4; ++r) {
      const int n = wr + mi * 16 + fg * 4 + r;
      yg[(rbase + n) * 512 + col0 + wc + fr]      = __float2bfloat16(acc2[mi][0][r]);
      yg[(rbase + n) * 512 + col0 + wc + 16 + fr] = __float2bfloat16(acc2[mi][1][r]);
    }
}

// ---------------------------------------------------------------------------
// Prep kernels (proven).
// ---------------------------------------------------------------------------
__global__ __launch_bounds__(256) void wconv_all_kernel(
    const float* __restrict__ bwq, const float* __restrict__ bwk,
    const float* __restrict__ bwv, const float* __restrict__ bwp,
    const float* __restrict__ bw1, const float* __restrict__ bw2,
    const float* __restrict__ wh1,
    __hip_bfloat16* __restrict__ wSelf, __hip_bfloat16* __restrict__ wCq,
    __hip_bfloat16* __restrict__ wCkv, __hip_bfloat16* __restrict__ wTp,
    __hip_bfloat16* __restrict__ wTw1, __hip_bfloat16* __restrict__ wTw2,
    __hip_bfloat16* __restrict__ wTh1) {
  const size_t MAT = (size_t)D * D;
  const size_t SS = (size_t)1536 * 512, KV = (size_t)1024 * 512;
  const int z = blockIdx.z;
  const float* src;
  __hip_bfloat16* dst;
  if (z < 8)       { int i = z >> 1; src = bwq + (size_t)z * MAT;
                     dst = (z & 1) ? wCq + (size_t)i * MAT : wSelf + (size_t)i * SS; }
  else if (z < 16) { int zz = z - 8, i = zz >> 1; src = bwk + (size_t)zz * MAT;
                     dst = (zz & 1) ? wCkv + (size_t)i * KV
                                    : wSelf + (size_t)i * SS + 512 * 512; }
  else if (z < 24) { int zz = z - 16, i = zz >> 1; src = bwv + (size_t)zz * MAT;
                     dst = (zz & 1) ? wCkv + (size_t)i * KV + 512 * 512
                                    : wSelf + (size_t)i * SS + 1024 * 512; }
  else if (z < 32) { int zz = z - 24; src = bwp + (size_t)zz * MAT; dst = wTp + (size_t)zz * MAT; }
  else if (z < 36) { int zz = z - 32; src = bw1 + (size_t)zz * MAT; dst = wTw1 + (size_t)zz * MAT; }
  else if (z < 40) { int zz = z - 36; src = bw2 + (size_t)zz * MAT; dst = wTw2 + (size_t)zz * MAT; }
  else             { src = wh1; dst = wTh1; }

  __shared__ float tile[32][33];
  const int r0 = blockIdx.y * 32, c0 = blockIdx.x * 32;
  const int tr = threadIdx.x >> 5;
  const int tc = threadIdx.x & 31;
#pragma unroll
  for (int i = 0; i < 4; ++i)
    tile[tr + 8 * i][tc] = src[(size_t)(r0 + tr + 8 * i) * D + c0 + tc];
  __syncthreads();
#pragma unroll
  for (int i = 0; i < 4; ++i)
    dst[(size_t)(c0 + tr + 8 * i) * D + r0 + tc] = __float2bfloat16(tile[tc][tr + 8 * i]);
}

__global__ __launch_bounds__(256) void misc_prep_kernel(
    const float* __restrict__ w_ae, const float* __restrict__ wh2,
    const float* __restrict__ bbq, const float* __restrict__ bbk,
    const float* __restrict__ bbv, const float* __restrict__ action,
    const float* __restrict__ obs_rep,
    __hip_bfloat16* __restrict__ waeT, __hip_bfloat16* __restrict__ wh2p,
    float* __restrict__ selfb, float* __restrict__ ckvb,
    float* __restrict__ bqc, __hip_bfloat16* __restrict__ actb,
    __hip_bfloat16* __restrict__ orb) {
  constexpr int R0 = 512 * 96, R1 = 128 * 512, R2 = NBLK * 1536,
                R3 = NBLK * 1024, R4 = NBLK * 512, R5 = M * 96;
  constexpr int R6 = M * D / 4;
  constexpr int total = R0 + R1 + R2 + R3 + R4 + R5 + R6;
  for (int i = blockIdx.x * 256 + threadIdx.x; i < total; i += gridDim.x * 256) {
    int j = i;
    if (j < R0) {
      const int n = j / 96, k = j - n * 96;
      waeT[j] = (k < 65) ? __float2bfloat16(w_ae[(size_t)k * 512 + n]) : __float2bfloat16(0.f);
    } else if ((j -= R0) < R1) {
      const int n = j >> 9, k = j & 511;
      wh2p[j] = (n < 64) ? __float2bfloat16(wh2[(size_t)k * 64 + n]) : __float2bfloat16(0.f);
    } else if ((j -= R1) < R2) {
      const int blk = j / 1536, c = j - blk * 1536;
      const int seg = c >> 9, cc = c & 511;
      const float* s = (seg == 0) ? bbq : (seg == 1) ? bbk : bbv;
      selfb[j] = s[(size_t)(blk * 2) * 512 + cc];
    } else if ((j -= R2) < R3) {
      const int blk = j >> 10, c = j & 1023;
      ckvb[j] = (c < 512) ? bbk[(size_t)(blk * 2 + 1) * 512 + c]
                          : bbv[(size_t)(blk * 2 + 1) * 512 + (c - 512)];
    } else if ((j -= R3) < R4) {
      const int blk = j >> 9, c = j & 511;
      bqc[j] = bbq[(size_t)(blk * 2 + 1) * 512 + c];
    } else if ((j -= R4) < R5) {
      const int row = j / 96, k = j - row * 96;
      actb[j] = (k < 65) ? __float2bfloat16(action[(size_t)row * 65 + k]) : __float2bfloat16(0.f);
    } else {
      j -= R5;
      const float4 v = reinterpret_cast<const float4*>(obs_rep)[j];
      ushort4 o;
      o.x = f2b_bits(v.x); o.y = f2b_bits(v.y);
      o.z = f2b_bits(v.z); o.w = f2b_bits(v.w);
      reinterpret_cast<ushort4*>(orb)[j] = o;
    }
  }
}

}  // namespace

extern "C" void kernel_launch(void* const* d_in, const int* in_sizes, int n_in,
                              void* d_out, int out_size, void* d_ws, size_t ws_size,
                              hipStream_t stream) {
  const float* action  = (const float*)d_in[0];
  const float* obs_rep = (const float*)d_in[1];
  const float* w_ae    = (const float*)d_in[3];
  const float* ln0_g   = (const float*)d_in[4];
  const float* ln0_b   = (const float*)d_in[5];
  const float* bln_g   = (const float*)d_in[6];
  const float* bln_b   = (const float*)d_in[7];
  const float* bwq     = (const float*)d_in[8];
  const float* bwk     = (const float*)d_in[9];
  const float* bwv     = (const float*)d_in[10];
  const float* bwp     = (const float*)d_in[11];
  const float* bbq     = (const float*)d_in[12];
  const float* bbk     = (const float*)d_in[13];
  const float* bbv     = (const float*)d_in[14];
  const float* bbp     = (const float*)d_in[15];
  const float* bw1     = (const float*)d_in[16];
  const float* bb1     = (const float*)d_in[17];
  const float* bw2     = (const float*)d_in[18];
  const float* bb2     = (const float*)d_in[19];
  const float* wh1     = (const float*)d_in[20];
  const float* bh1     = (const float*)d_in[21];
  const float* lnh_g   = (const float*)d_in[22];
  const float* lnh_b   = (const float*)d_in[23];
  const float* wh2     = (const float*)d_in[24];
  const float* bh2     = (const float*)d_in[25];

  char* ws = (char*)d_ws;
  const size_t MAT = (size_t)D * D;
  const size_t szB = (size_t)M * D * 2;

  __hip_bfloat16* xb  = (__hip_bfloat16*)ws; ws += szB;
  __hip_bfloat16* hb  = (__hip_bfloat16*)ws; ws += szB;
  __hip_bfloat16* vtb = (__hip_bfloat16*)ws; ws += szB;
  __hip_bfloat16* orb = (__hip_bfloat16*)ws; ws += szB;
  __hip_bfloat16* qkb = (__hip_bfloat16*)ws; ws += 2 * szB;
  __hip_bfloat16* qcb = (__hip_bfloat16*)ws; ws += 4 * szB;
  __hip_bfloat16* kb  = (__hip_bfloat16*)ws; ws += szB;
  __hip_bfloat16* actb = (__hip_bfloat16*)ws; ws += (size_t)M * 96 * 2;
  __hip_bfloat16* wSelf = (__hip_bfloat16*)ws; ws += (size_t)NBLK * 1536 * 512 * 2;
  __hip_bfloat16* wCq   = (__hip_bfloat16*)ws; ws += (size_t)NBLK * 512 * 512 * 2;
  __hip_bfloat16* wCkv  = (__hip_bfloat16*)ws; ws += (size_t)NBLK * 1024 * 512 * 2;
  __hip_bfloat16* wTp   = (__hip_bfloat16*)ws; ws += 8 * MAT * 2;
  __hip_bfloat16* wTw1  = (__hip_bfloat16*)ws; ws += 4 * MAT * 2;
  __hip_bfloat16* wTw2  = (__hip_bfloat16*)ws; ws += 4 * MAT * 2;
  __hip_bfloat16* wTh1  = (__hip_bfloat16*)ws; ws += MAT * 2;
  __hip_bfloat16* wh2p  = (__hip_bfloat16*)ws; ws += 128 * 512 * 2;
  __hip_bfloat16* waeT  = (__hip_bfloat16*)ws; ws += 512 * 96 * 2;
  float* selfb         = (float*)ws;         ws += (size_t)NBLK * 1536 * 4;
  float* ckvb          = (float*)ws;         ws += (size_t)NBLK * 1024 * 4;
  float* bqc           = (float*)ws;         ws += (size_t)NBLK * 512 * 4;

  // ---- prep: 2 dispatches ----
  wconv_all_kernel<<<dim3(16, 16, 41), 256, 0, stream>>>(
      bwq, bwk, bwv, bwp, bw1, bw2, wh1,
      wSelf, wCq, wCkv, wTp, wTw1, wTw2, wTh1);
  misc_prep_kernel<<<2048, 256, 0, stream>>>(
      w_ae, wh2, bbq, bbk, bbv, action, obs_rep,
      waeT, wh2p, selfb, ckvb, bqc, actb, orb);

  const size_t SS = (size_t)1536 * 512;
  const size_t KV = (size_t)1024 * 512;
  const int lnGrid = M / 64;

  // ---- encoder ----
  gemm_ln_enc_kernel<<<lnGrid, 512, 0, stream>>>(actb, waeT, ln0_g, ln0_b, xb);

  // ---- batched cross-attention Q for all 4 blocks ----
  gemm_dp_kernel<false, NEVER><<<M / 128 * 8, 512, 0, stream>>>(
      orb, wCq, bqc, qcb, 2048, nullptr, 8);

  for (int i = 0; i < NBLK; ++i) {
    const float* g0 = bln_g + (size_t)(i * 3 + 0) * D;
    const float* b0 = bln_b + (size_t)(i * 3 + 0) * D;
    const float* g1 = bln_g + (size_t)(i * 3 + 1) * D;
    const float* b1 = bln_b + (size_t)(i * 3 + 1) * D;
    const float* g2 = bln_g + (size_t)(i * 3 + 2) * D;
    const float* b2 = bln_b + (size_t)(i * 3 + 2) * D;

    // sublayer 1: self-attention
    gemm_dp_kernel<false, 1024><<<M / 128 * 6, 512, 0, stream>>>(
        xb, wSelf + (size_t)i * SS, selfb + (size_t)i * 1536, qkb, 1024, vtb, 6);
    attn_mfma_kernel<<<B * H, 256, 0, stream>>>(qkb, 1024, qkb + 512, 1024, vtb, hb);
    gemm_ln64_kernel<false, true><<<lnGrid, 512, 0, stream>>>(
        hb, wTp + (size_t)(i * 2) * MAT, bbp + (size_t)(i * 2) * D, xb, g0, b0, xb);

    // sublayer 2: cross-attention
    gemm_dp_kernel<false, 512><<<M / 128 * 4, 512, 0, stream>>>(
        xb, wCkv + (size_t)i * KV, ckvb + (size_t)i * 1024, kb, 512, vtb, 4);
    attn_mfma_kernel<<<B * H, 256, 0, stream>>>(
        qcb + (size_t)i * 512, 2048, kb, 512, vtb, hb);
    gemm_ln64_kernel<false, true><<<lnGrid, 512, 0, stream>>>(
        hb, wTp + (size_t)(i * 2 + 1) * MAT, bbp + (size_t)(i * 2 + 1) * D,
        orb, g1, b1, xb);

    // sublayer 3: MLP
    gemm_dp_kernel<true, NEVER><<<M / 128 * 2, 512, 0, stream>>>(
        xb, wTw1 + (size_t)i * MAT, bb1 + (size_t)i * D, hb, 512, nullptr, 2);
    gemm_ln64_kernel<false, true><<<lnGrid, 512, 0, stream>>>(
        hb, wTw2 + (size_t)i * MAT, bb2 + (size_t)i * D, xb, g2, b2, xb);
  }

  // ---- head: GEMM+GELU+LN then small GEMM ----
  gemm_ln64_kernel<true, false><<<lnGrid, 512, 0, stream>>>(
      xb, wTh1, bh1, nullptr, lnh_g, lnh_b, hb);
  gemm_head_kernel<16><<<dim3(M / 128, 1), 256, 0, stream>>>(
      hb, wh2p, bh2, (float*)d_out, 64, 64);
}